// Round 2
// baseline (183.149 us; speedup 1.0000x reference)
//
#include <hip/hip_runtime.h>
#include <hip/hip_bf16.h>

// BoundarySeg: B=16, L=1024, H=768, MAX_SPAN_LEN=6 — ALL FP32
//   w[b,j,d]     = span[b, j, min(j+d,L-1), 0] * (j+d < L)
//   first[b,j,h] = sum_d w[b,j,d] * bound[b, min(j+d,L-1), h]
//   second[b,j,h]= bound[b,j,h] * sum_d w[b,j,d]
//   out = concat(first, second, axis=-1)  -> (B, L, 1536)
//
// Round-1 post-mortem: NaNs proved the device buffers are fp32 (reading fp32
// bit patterns as bf16 pairs yields NaN from random mantissa bits); the
// "bf16" in the harness error label is an unconditional string, not a dtype
// indicator. Memory-bound: ~152 MB total traffic -> ~24 us floor at 6.3 TB/s.

#define LROWS 1024
#define HDIM  768
#define SPANW 6
#define VEC_PER_ROW (HDIM / 4)   // 192 float4 per row-half

__global__ __launch_bounds__(256) void boundary_seg_kernel(
    const float* __restrict__ span,   // (B, L, L, 1)
    const float* __restrict__ bound,  // (B, L, H)
    float* __restrict__ out)          // (B, L, 2H)
{
    const int v  = blockIdx.x * 256 + threadIdx.x;   // global float4 id
    const int hv = v % VEC_PER_ROW;                  // float4 index within row
    const int t  = v / VEC_PER_ROW;                  // b*L + j
    const int j  = t & (LROWS - 1);
    const int bL = t - j;                            // b*L

    // --- span weights: 6 contiguous fp32 on the diagonal band of row (b,j)
    const float* srow = span + (size_t)t * LROWS + j;
    float w[SPANW];
    float wsum = 0.f;
#pragma unroll
    for (int d = 0; d < SPANW; ++d) {
        float wd = 0.f;
        if (j + d < LROWS) wd = srow[d];
        w[d] = wd;
        wsum += wd;
    }

    // --- windowed weighted sum over 6 rows of bound_hidden
    float4 acc = make_float4(0.f, 0.f, 0.f, 0.f);
    float4 h0;
#pragma unroll
    for (int d = 0; d < SPANW; ++d) {
        int row = j + d;
        if (row > LROWS - 1) row = LROWS - 1;        // clamped; w[d]=0 if invalid
        const float4 h =
            *(const float4*)(bound + (size_t)(bL + row) * HDIM + hv * 4);
        if (d == 0) h0 = h;                          // bound[b, j, :] slice
        acc.x += w[d] * h.x;
        acc.y += w[d] * h.y;
        acc.z += w[d] * h.z;
        acc.w += w[d] * h.w;
    }

    const float4 sec = make_float4(h0.x * wsum, h0.y * wsum,
                                   h0.z * wsum, h0.w * wsum);

    float* orow = out + (size_t)t * (2 * HDIM) + hv * 4;
    *(float4*)(orow)        = acc;
    *(float4*)(orow + HDIM) = sec;
}

extern "C" void kernel_launch(void* const* d_in, const int* in_sizes, int n_in,
                              void* d_out, int out_size, void* d_ws, size_t ws_size,
                              hipStream_t stream) {
    const float* span  = (const float*)d_in[0];
    const float* bound = (const float*)d_in[1];
    float* out = (float*)d_out;

    const int B = in_sizes[1] / (LROWS * HDIM);      // 16
    const int total_vecs = B * LROWS * VEC_PER_ROW;  // 3,145,728
    dim3 grid(total_vecs / 256), block(256);
    hipLaunchKernelGGL(boundary_seg_kernel, grid, block, 0, stream,
                       span, bound, out);
}

// Round 4
// 182.945 us; speedup vs baseline: 1.0011x; 1.0011x over previous
//
#include <hip/hip_runtime.h>
#include <hip/hip_bf16.h>

// BoundarySeg: B=16, L=1024, H=768, MAX_SPAN_LEN=6 — ALL FP32
//   w[b,j,d]     = span[b, j, min(j+d,L-1), 0] * (j+d < L)
//   first[b,j,h] = sum_d w[b,j,d] * bound[b, min(j+d,L-1), h]
//   second[b,j,h]= bound[b,j,h] * sum_d w[b,j,d]
//   out = concat(first, second, axis=-1)  -> (B, L, 1536)
//
// R2 post-mortem: flat kernel ran ~60 us ≈ 400 MB at the 6.6 TB/s ceiling
// (calibrated by the harness fill kernels) — the 6x windowed re-read of
// bound_hidden missed cache (adjacent blocks land on different XCDs).
// R3/R4: LDS-tile 8 rows/block, stage 13 bound rows once -> amplification
// 6x -> 1.63x; predicted kernel ~30 us (FETCH ~85 MB, WRITE ~100 MB).
// R4 fix: __builtin_nontemporal_store needs ext_vector_type, not HIP float4.

#define LROWS 1024
#define HDIM  768
#define SPANW 6
#define TILE_J 8
#define STAGE (TILE_J + SPANW - 1)      // 13 staged rows
#define VEC_PER_ROW (HDIM / 4)          // 192 float4 per row-half
#define WPT (TILE_J * VEC_PER_ROW / 256) // 6 outputs per thread

typedef float f32x4 __attribute__((ext_vector_type(4)));

__global__ __launch_bounds__(256) void boundary_seg_kernel(
    const float* __restrict__ span,   // (B, L, L, 1)
    const float* __restrict__ bound,  // (B, L, H)
    float* __restrict__ out)          // (B, L, 2H)
{
    __shared__ float sb[STAGE * HDIM];        // 39,936 B staged bound rows
    __shared__ float sw[TILE_J][SPANW];       // span weights
    __shared__ float swsum[TILE_J];

    const int tid = threadIdx.x;
    const int b   = blockIdx.x >> 7;                  // / (1024/TILE_J)
    const int j0  = (blockIdx.x & 127) * TILE_J;      // first row of tile
    const int bL  = b * LROWS;

    // --- stage bound rows j0 .. j0+12 (clamped to last row) into LDS
    //     slot s holds row min(j0+s, L-1)  -> compute loop needs no clamp
    f32x4* sb4 = (f32x4*)sb;
    for (int i = tid; i < STAGE * VEC_PER_ROW; i += 256) {
        const int s  = i / VEC_PER_ROW;
        const int hv = i % VEC_PER_ROW;
        int gr = j0 + s;
        if (gr > LROWS - 1) gr = LROWS - 1;
        sb4[i] = *(const f32x4*)(bound + (size_t)(bL + gr) * HDIM + hv * 4);
    }

    // --- span weights: one thread per tile row
    if (tid < TILE_J) {
        const int j = j0 + tid;
        const float* srow = span + (size_t)(bL + j) * LROWS + j;
        float wsum = 0.f;
#pragma unroll
        for (int d = 0; d < SPANW; ++d) {
            float wd = (j + d < LROWS) ? srow[d] : 0.f;
            sw[tid][d] = wd;
            wsum += wd;
        }
        swsum[tid] = wsum;
    }
    __syncthreads();

    // --- compute: each thread produces WPT f32x4 outputs (both halves)
#pragma unroll
    for (int k = 0; k < WPT; ++k) {
        const int item = tid + k * 256;
        const int jj   = item / VEC_PER_ROW;          // tile row 0..7
        const int hv   = item % VEC_PER_ROW;

        f32x4 acc = (f32x4)(0.f);
        f32x4 h0;
#pragma unroll
        for (int d = 0; d < SPANW; ++d) {
            const float wd = sw[jj][d];
            const f32x4 h = sb4[(jj + d) * VEC_PER_ROW + hv];
            if (d == 0) h0 = h;
            acc += wd * h;
        }
        const f32x4 sec = h0 * swsum[jj];

        float* orow = out + (size_t)(bL + j0 + jj) * (2 * HDIM) + hv * 4;
        __builtin_nontemporal_store(acc, (f32x4*)orow);
        __builtin_nontemporal_store(sec, (f32x4*)(orow + HDIM));
    }
}

extern "C" void kernel_launch(void* const* d_in, const int* in_sizes, int n_in,
                              void* d_out, int out_size, void* d_ws, size_t ws_size,
                              hipStream_t stream) {
    const float* span  = (const float*)d_in[0];
    const float* bound = (const float*)d_in[1];
    float* out = (float*)d_out;

    const int B = in_sizes[1] / (LROWS * HDIM);          // 16
    dim3 grid(B * (LROWS / TILE_J)), block(256);         // 2048 x 256
    hipLaunchKernelGGL(boundary_seg_kernel, grid, block, 0, stream,
                       span, bound, out);
}